// Round 14
// baseline (91.714 us; speedup 1.0000x reference)
//
#include <hip/hip_runtime.h>
#include <stdint.h>

typedef unsigned short u16;
using bf16x8 = __attribute__((ext_vector_type(8))) short;
using f32x4  = __attribute__((ext_vector_type(4))) float;
using f32x16 = __attribute__((ext_vector_type(16))) float;
typedef unsigned int uv2 __attribute__((ext_vector_type(2)));

#define EPS_GN 1e-5f
#define SCL 0.18033688011112042f   // 0.125 * log2(e)

__device__ __forceinline__ u16 f2bf(float f) {
  union { float f; uint32_t u; } x; x.f = f;
  uint32_t r = x.u + 0x7FFFu + ((x.u >> 16) & 1u);
  return (u16)(r >> 16);
}

__device__ __forceinline__ void gload_lds16(const void* g, void* l) {
  __builtin_amdgcn_global_load_lds(
      (const __attribute__((address_space(1))) unsigned int*)g,
      (__attribute__((address_space(3))) unsigned int*)l, 16, 0, 0);
}

__device__ __forceinline__ void fence_tile() {
  asm volatile("s_waitcnt vmcnt(0)" ::: "memory");
  __builtin_amdgcn_s_barrier();
  __builtin_amdgcn_sched_barrier(0);
}

// ---------------- prep: GN partial sums (blocks 0..511) + weight cvt (blocks 512..1535) ----------------
__global__ __launch_bounds__(256) void prep(const float* __restrict__ x,
    float* __restrict__ part,
    const float4* __restrict__ wq, const float4* __restrict__ wk,
    const float4* __restrict__ wv, const float4* __restrict__ wp,
    const float* __restrict__ bq, const float* __restrict__ bk,
    const float* __restrict__ bv,
    u16* __restrict__ wqkv, u16* __restrict__ wpb, float* __restrict__ bqkv) {
  if (blockIdx.x < 512) {
    int bg = blockIdx.x >> 3, seg = blockIdx.x & 7;
    const float4* base = (const float4*)(x + (size_t)bg * 65536 + (size_t)seg * 8192);
    float s = 0.f, s2 = 0.f;
    for (int i = threadIdx.x; i < 2048; i += 256) {
      float4 v = base[i];
      s  += v.x + v.y + v.z + v.w;
      s2 += v.x*v.x + v.y*v.y + v.z*v.z + v.w*v.w;
    }
    for (int m = 1; m < 64; m <<= 1) { s += __shfl_xor(s, m); s2 += __shfl_xor(s2, m); }
    __shared__ float red[4][2];
    int wave = threadIdx.x >> 6;
    if ((threadIdx.x & 63) == 0) { red[wave][0] = s; red[wave][1] = s2; }
    __syncthreads();
    if (threadIdx.x == 0) {
      float a = 0.f, b = 0.f;
      for (int w = 0; w < 4; ++w) { a += red[w][0]; b += red[w][1]; }
      part[blockIdx.x * 2] = a; part[blockIdx.x * 2 + 1] = b;
    }
  } else {
    int i = (blockIdx.x - 512) * 256 + threadIdx.x;     // 0..262143
    int seg = i >> 16, j = i & 65535;
    const float4* w = (seg == 0) ? wq : (seg == 1) ? wk : (seg == 2) ? wv : wp;
    u16* o = (seg < 3) ? (wqkv + seg * 262144) : wpb;
    float sc = (seg == 0) ? SCL : 1.f;
    float4 v = w[j];
    o[j*4+0] = f2bf(v.x*sc); o[j*4+1] = f2bf(v.y*sc);
    o[j*4+2] = f2bf(v.z*sc); o[j*4+3] = f2bf(v.w*sc);
    if (i < 1536) bqkv[i] = (i < 512) ? bq[i]*SCL : (i < 1024) ? bk[i-512] : bv[i-1024];
  }
}

// ---------------- GN normalize + transpose [B,C,S] -> xn bf16 [B,S,C] (stats inline) ----------------
__global__ __launch_bounds__(256) void gn_apply(const float* __restrict__ x,
    const float* __restrict__ part, const float* __restrict__ w,
    const float* __restrict__ bb, u16* __restrict__ xn) {
  __shared__ float t[32][33];
  int s0 = blockIdx.x * 32, c0 = blockIdx.y * 32, b = blockIdx.z;
  int g = c0 >> 6;
  float s = 0.f, s2 = 0.f;
  for (int q = 0; q < 8; ++q) {
    s  += part[((b*8+g)*8 + q)*2];
    s2 += part[((b*8+g)*8 + q)*2 + 1];
  }
  float mean = s * (1.f/65536.f);
  float rstd = rsqrtf(s2 * (1.f/65536.f) - mean*mean + EPS_GN);
  for (int i = 0; i < 4; ++i) {
    int c = c0 + threadIdx.y + i * 8;
    float v = x[((size_t)b*512 + c)*1024 + s0 + threadIdx.x];
    t[threadIdx.y + i*8][threadIdx.x] = (v - mean) * rstd * w[c] + bb[c];
  }
  __syncthreads();
  for (int i = 0; i < 4; ++i) {
    int sdx = s0 + threadIdx.y + i * 8;
    xn[((size_t)b*1024 + sdx)*512 + c0 + threadIdx.x] = f2bf(t[threadIdx.x][threadIdx.y + i*8]);
  }
}

// ---------------- fused QKV GEMM: Out[m][n] = X[m][:]·W[n][:] + bias[n] ----------------
// 64(m) x 128(n) tiles, grid 1536. cols 0..511 -> qb row-major [8192][512]
// cols 512..1023 -> K fragment-packed; cols 1024..1535 -> V fragment-packed
__global__ __launch_bounds__(256) void qkv_gemm(const u16* __restrict__ X,
    const u16* __restrict__ W, const float* __restrict__ bias,
    u16* __restrict__ qb, u16* __restrict__ kP, u16* __restrict__ vP) {
  __shared__ __align__(16) u16 As[2*64*64];      // 16KB
  __shared__ __align__(16) u16 Bs[2*128*64];     // 32KB
  const int K = 512;
  int m0 = (blockIdx.x & 127) * 64, n0 = (blockIdx.x >> 7) * 128;
  int t = threadIdx.x, lane = t & 63, wave = t >> 6;
  int wm = wave >> 1, wn = wave & 1;
  int lr = lane & 15, lg = lane >> 4;
  f32x4 acc[2][4] = {};

  auto stage = [&](int k0, int bufi) {
    u16* Ab = As + bufi * 4096;
    u16* Bb = Bs + bufi * 8192;
#pragma unroll
    for (int c = 0; c < 2; ++c) {
      int chunk = wave * 2 + c;
      int e = chunk * 512 + lane * 8;
      int r = e >> 6, col = e & 63;
      int scol = col ^ ((r & 7) << 3);
      gload_lds16(X + (size_t)(m0 + r) * K + k0 + scol, (char*)Ab + chunk * 1024);
    }
#pragma unroll
    for (int c = 0; c < 4; ++c) {
      int chunk = wave * 4 + c;
      int e = chunk * 512 + lane * 8;
      int r = e >> 6, col = e & 63;
      int scol = col ^ ((r & 7) << 3);
      gload_lds16(W + (size_t)(n0 + r) * K + k0 + scol, (char*)Bb + chunk * 1024);
    }
  };

  stage(0, 0);
  fence_tile();
  int buf = 0;
  for (int k0 = 0; k0 < K; k0 += 64) {
    if (k0 + 64 < K) stage(k0 + 64, buf ^ 1);
    const char* Ab = (const char*)(As + buf * 4096);
    const char* Bb = (const char*)(Bs + buf * 8192);
    bf16x8 af[2][2], bfr[4][2];
#pragma unroll
    for (int kk = 0; kk < 2; ++kk) {
      int ca = kk * 64 + lg * 16;
#pragma unroll
      for (int i = 0; i < 2; ++i) {
        int ra = wm * 32 + i * 16 + lr;
        af[i][kk] = *(const bf16x8*)(Ab + ((ra * 128 + ca) ^ ((ra & 7) << 4)));
      }
#pragma unroll
      for (int j = 0; j < 4; ++j) {
        int rb = wn * 64 + j * 16 + lr;
        bfr[j][kk] = *(const bf16x8*)(Bb + ((rb * 128 + ca) ^ ((rb & 7) << 4)));
      }
    }
    __builtin_amdgcn_s_setprio(1);
#pragma unroll
    for (int kk = 0; kk < 2; ++kk)
#pragma unroll
      for (int i = 0; i < 2; ++i)
#pragma unroll
        for (int j = 0; j < 4; ++j)
          acc[i][j] = __builtin_amdgcn_mfma_f32_16x16x32_bf16(af[i][kk], bfr[j][kk], acc[i][j], 0, 0, 0);
    __builtin_amdgcn_s_setprio(0);
    fence_tile();
    buf ^= 1;
  }
  if (n0 < 512) {
    for (int i = 0; i < 2; ++i)
      for (int j = 0; j < 4; ++j) {
        int col = n0 + wn * 64 + j * 16 + lr;
        float bv = bias[col];
        int rowb = m0 + wm * 32 + i * 16 + lg * 4;
        for (int r = 0; r < 4; ++r)
          qb[(size_t)(rowb + r) * 512 + col] = f2bf(acc[i][j][r] + bv);
      }
  } else if (n0 < 1024) {
    for (int i = 0; i < 2; ++i)
      for (int j = 0; j < 4; ++j) {
        int col = n0 + wn * 64 + j * 16 + lr;
        float bv = bias[col];
        int colK = col - 512;
        int h = colK >> 6, dcol = colK & 63;
        int s = dcol >> 4, hi2 = (dcol >> 3) & 1, jj = dcol & 7;
        int rowb = m0 + wm * 32 + i * 16 + lg * 4;
        int bb2 = rowb >> 10, s_in = rowb & 1023;
        int tile = s_in >> 6, kvl = s_in & 63;
        int n2 = kvl >> 5, lq0 = kvl & 31;
        size_t base = ((size_t)(((h * 8 + bb2) * 16 + tile) * 8 + n2 * 4 + s)) * 512 + jj;
        for (int r = 0; r < 4; ++r)
          kP[base + (size_t)(hi2 * 32 + lq0 + r) * 8] = f2bf(acc[i][j][r] + bv);
      }
  } else {
    for (int i = 0; i < 2; ++i)
      for (int j = 0; j < 4; ++j) {
        int col = n0 + wn * 64 + j * 16 + lr;
        float bv = bias[col];
        int rowb = m0 + wm * 32 + i * 16 + lg * 4;
        int colV = col - 1024;
        int h  = colV >> 6, dl = colV & 63;
        int dt = dl >> 5,  lqv = dl & 31;
        int bb2 = rowb >> 10, s_in = rowb & 1023;
        int tile = s_in >> 6, kvl = s_in & 63;
        int cg = kvl >> 4, hiv = (kvl >> 3) & 1, j0 = kvl & 7;
        int ii = dt * 4 + cg, lv = hiv * 32 + lqv;
        size_t u16off = ((size_t)((h * 8 + bb2) * 16 + tile)) * 4096 + (ii * 64 + lv) * 8 + j0;
        unsigned p0, p1;
        float v0 = acc[i][j][0] + bv, v1 = acc[i][j][1] + bv;
        float v2 = acc[i][j][2] + bv, v3 = acc[i][j][3] + bv;
        asm("v_cvt_pk_bf16_f32 %0, %1, %2" : "=v"(p0) : "v"(v0), "v"(v1));
        asm("v_cvt_pk_bf16_f32 %0, %1, %2" : "=v"(p1) : "v"(v2), "v"(v3));
        uint2 pk; pk.x = p0; pk.y = p1;
        *(uint2*)(vP + u16off) = pk;
      }
  }
}

// ---------------- final projection (swapped): out[b][c][s] = Wp[c]·att[s][:] + bp[c] + x ----------------
__global__ __launch_bounds__(256) void proj_gemm(const u16* __restrict__ Wt,
    const u16* __restrict__ X, const float* __restrict__ bias,
    const float* __restrict__ resid, float* __restrict__ Out) {
  __shared__ __align__(16) u16 As[2*128*64];
  __shared__ __align__(16) u16 Bs[2*64*64];
  const int K = 512;
  int m0 = blockIdx.x * 64, n0 = blockIdx.y * 128;
  int t = threadIdx.x, lane = t & 63, wave = t >> 6;
  int wm = wave >> 1, wn = wave & 1;
  int lr = lane & 15, lg = lane >> 4;
  f32x4 acc[4][2] = {};

  auto stage = [&](int k0, int bufi) {
    u16* Ab = As + bufi * 8192;
    u16* Bb = Bs + bufi * 4096;
#pragma unroll
    for (int c = 0; c < 4; ++c) {
      int chunk = wave * 4 + c;
      int e = chunk * 512 + lane * 8;
      int r = e >> 6, col = e & 63;
      int scol = col ^ ((r & 7) << 3);
      gload_lds16(Wt + (size_t)(n0 + r) * K + k0 + scol, (char*)Ab + chunk * 1024);
    }
#pragma unroll
    for (int c = 0; c < 2; ++c) {
      int chunk = wave * 2 + c;
      int e = chunk * 512 + lane * 8;
      int r = e >> 6, col = e & 63;
      int scol = col ^ ((r & 7) << 3);
      gload_lds16(X + (size_t)(m0 + r) * K + k0 + scol, (char*)Bb + chunk * 1024);
    }
  };

  stage(0, 0);
  fence_tile();
  int buf = 0;
  for (int k0 = 0; k0 < K; k0 += 64) {
    if (k0 + 64 < K) stage(k0 + 64, buf ^ 1);
    const char* Ab = (const char*)(As + buf * 8192);
    const char* Bb = (const char*)(Bs + buf * 4096);
    bf16x8 af[4][2], bfr[2][2];
#pragma unroll
    for (int kk = 0; kk < 2; ++kk) {
      int ca = kk * 64 + lg * 16;
#pragma unroll
      for (int i = 0; i < 4; ++i) {
        int ra = wm * 64 + i * 16 + lr;
        af[i][kk] = *(const bf16x8*)(Ab + ((ra * 128 + ca) ^ ((ra & 7) << 4)));
      }
#pragma unroll
      for (int j = 0; j < 2; ++j) {
        int rb = wn * 32 + j * 16 + lr;
        bfr[j][kk] = *(const bf16x8*)(Bb + ((rb * 128 + ca) ^ ((rb & 7) << 4)));
      }
    }
    __builtin_amdgcn_s_setprio(1);
#pragma unroll
    for (int kk = 0; kk < 2; ++kk)
#pragma unroll
      for (int i = 0; i < 4; ++i)
#pragma unroll
        for (int j = 0; j < 2; ++j)
          acc[i][j] = __builtin_amdgcn_mfma_f32_16x16x32_bf16(af[i][kk], bfr[j][kk], acc[i][j], 0, 0, 0);
    __builtin_amdgcn_s_setprio(0);
    fence_tile();
    buf ^= 1;
  }
  for (int i = 0; i < 4; ++i)
    for (int j = 0; j < 2; ++j) {
      int mcol = m0 + wn * 32 + j * 16 + lr;
      for (int r = 0; r < 4; ++r) {
        int nrow = n0 + wm * 64 + i * 16 + lg * 4 + r;
        float v = acc[i][j][r] + bias[nrow];
        size_t b = (size_t)(mcol >> 10); int s = mcol & 1023;
        size_t addr = (b * 512 + nrow) * 1024 + s;
        Out[addr] = v + resid[addr];
      }
    }
}

// ---------------- flash attention: 64 q-rows/wave (2 groups share K/V loads), KV-split x2 ----------------
// grid (64 bh, 4 qb2); 8 waves x 512 thr; launch_bounds(512,2) -> 256 VGPR budget.
// Per tile: QK-A -> issue vr -> QK-B -> exp2 A,B -> frA,frB -> prefetch kf_next -> sums -> PV-A,PV-B.
__global__ __launch_bounds__(512, 2) void attn_fwd(const u16* __restrict__ qbuf,
    const u16* __restrict__ kP, const u16* __restrict__ vP, u16* __restrict__ o) {
  __shared__ float comb[4][2112];                 // 33KB: per wq4 [dt*16+r][lane] + li
  __shared__ __align__(16) u16 wbuf[4][2048];     // 16KB transpose buffers
  int bh = blockIdx.x, qb2 = blockIdx.y;
  int b = bh >> 3, h = bh & 7;
  int t = threadIdx.x, lane = t & 63, wave = t >> 6;
  int half = wave >> 2, wq4 = wave & 3;
  int lq = lane & 31, hi = lane >> 5;
  int qrow0 = qb2 * 256 + wq4 * 64;
  bf16x8 qf[2][4];
#pragma unroll
  for (int g = 0; g < 2; ++g) {
    const u16* qp = qbuf + (size_t)(b * 1024 + qrow0 + g * 32 + lq) * 512 + h * 64 + hi * 8;
#pragma unroll
    for (int s = 0; s < 4; ++s) qf[g][s] = *(const bf16x8*)(qp + s * 16);
  }
  float liA = 0.f, liB = 0.f;
  f32x16 otA0 = {}, otA1 = {}, otB0 = {}, otB1 = {};
  const u16* kb = kP + ((size_t)((h * 8 + b) * 16 + half * 8)) * 4096 + (size_t)lane * 8;
  const u16* vb = vP + ((size_t)((h * 8 + b) * 16 + half * 8)) * 4096 + (size_t)lane * 8;

  bf16x8 kfA[8], kfB[8];
#pragma unroll
  for (int f = 0; f < 8; ++f) kfA[f] = *(const bf16x8*)(kb + f * 512);

  auto tile_body = [&](int ti, bf16x8 (&kf)[8], bf16x8 (&kn)[8]) {
    // QK group A
    f32x16 stA[2];
#pragma unroll
    for (int n2 = 0; n2 < 2; ++n2) {
      f32x16 z = {};
      __builtin_amdgcn_s_setprio(1);
#pragma unroll
      for (int s = 0; s < 4; ++s)
        z = __builtin_amdgcn_mfma_f32_32x32x16_bf16(kf[n2 * 4 + s], qf[0][s], z, 0, 0, 0);
      __builtin_amdgcn_s_setprio(0);
      stA[n2] = z;
    }
    // issue V loads (hidden under QK-B + softmax)
    bf16x8 vr[8];
#pragma unroll
    for (int i = 0; i < 8; ++i) vr[i] = *(const bf16x8*)(vb + ti * 4096 + i * 512);
    // QK group B
    f32x16 stB[2];
#pragma unroll
    for (int n2 = 0; n2 < 2; ++n2) {
      f32x16 z = {};
      __builtin_amdgcn_s_setprio(1);
#pragma unroll
      for (int s = 0; s < 4; ++s)
        z = __builtin_amdgcn_mfma_f32_32x32x16_bf16(kf[n2 * 4 + s], qf[1][s], z, 0, 0, 0);
      __builtin_amdgcn_s_setprio(0);
      stB[n2] = z;
    }
    // max-free softmax in place
#pragma unroll
    for (int r = 0; r < 16; ++r) {
      stA[0][r] = __builtin_amdgcn_exp2f(stA[0][r]);
      stA[1][r] = __builtin_amdgcn_exp2f(stA[1][r]);
      stB[0][r] = __builtin_amdgcn_exp2f(stB[0][r]);
      stB[1][r] = __builtin_amdgcn_exp2f(stB[1][r]);
    }
    // P fragments
    bf16x8 frA[4], frB[4];
#pragma unroll
    for (int n2 = 0; n2 < 2; ++n2)
#pragma unroll
      for (int c = 0; c < 2; ++c) {
        unsigned W0, W1, W2, W3;
        asm("v_cvt_pk_bf16_f32 %0, %1, %2" : "=v"(W0) : "v"(stA[n2][8*c+0]), "v"(stA[n2][8*c+1]));
        asm("v_cvt_pk_bf16_f32 %0, %1, %2" : "=v"(W1) : "v"(stA[n2][8*c+2]), "v"(stA[n2][8*c+3]));
        asm("v_cvt_pk_bf16_f32 %0, %1, %2" : "=v"(W2) : "v"(stA[n2][8*c+4]), "v"(stA[n2][8*c+5]));
        asm("v_cvt_pk_bf16_f32 %0, %1, %2" : "=v"(W3) : "v"(stA[n2][8*c+6]), "v"(stA[n2][8*c+7]));
        uv2 r02 = __builtin_amdgcn_permlane32_swap(W0, W2, false, false);
        uv2 r13 = __builtin_amdgcn_permlane32_swap(W1, W3, false, false);
        union { unsigned u[4]; bf16x8 v; } f;
        f.u[0] = r02[0]; f.u[1] = r13[0]; f.u[2] = r02[1]; f.u[3] = r13[1];
        frA[n2 * 2 + c] = f.v;
      }
#pragma unroll
    for (int n2 = 0; n2 < 2; ++n2)
#pragma unroll
      for (int c = 0; c < 2; ++c) {
        unsigned W0, W1, W2, W3;
        asm("v_cvt_pk_bf16_f32 %0, %1, %2" : "=v"(W0) : "v"(stB[n2][8*c+0]), "v"(stB[n2][8*c+1]));
        asm("v_cvt_pk_bf16_f32 %0, %1, %2" : "=v"(W1) : "v"(stB[n2][8*c+2]), "v"(stB[n2][8*c+3]));
        asm("v_cvt_pk_bf16_f32 %0, %1, %2" : "=v"(W2) : "v"(stB[n2][8*c+4]), "v"(stB[n2][8*c+5]));
        asm("v_cvt_pk_bf16_f32 %0, %1, %2" : "=v"(W3) : "v"(stB[n2][8*c+6]), "v"(stB[n2][8*c+7]));
        uv2 r02 = __builtin_amdgcn_permlane32_swap(W0, W2, false, false);
        uv2 r13 = __builtin_amdgcn_permlane32_swap(W1, W3, false, false);
        union { unsigned u[4]; bf16x8 v; } f;
        f.u[0] = r02[0]; f.u[1] = r13[0]; f.u[2] = r02[1]; f.u[3] = r13[1];
        frB[n2 * 2 + c] = f.v;
      }
    // prefetch K for next tile (hidden under sums + PV)
    if (ti < 7) {
#pragma unroll
      for (int f = 0; f < 8; ++f) kn[f] = *(const bf16x8*)(kb + (ti + 1) * 4096 + f * 512);
    }
    // row sums (in place; lane32 shfl deferred)
#pragma unroll
    for (int r = 0; r < 16; ++r) { stA[0][r] += stA[1][r]; stB[0][r] += stB[1][r]; }
#pragma unroll
    for (int s = 8; s > 0; s >>= 1)
#pragma unroll
      for (int r = 0; r < s; ++r) { stA[0][r] += stA[0][r + s]; stB[0][r] += stB[0][r + s]; }
    liA += stA[0][0];
    liB += stB[0][0];
    // PV (dt-interleaved for ILP)
    __builtin_amdgcn_s_setprio(1);
#pragma unroll
    for (int cg = 0; cg < 4; ++cg) {
      otA0 = __builtin_amdgcn_mfma_f32_32x32x16_bf16(vr[cg],     frA[cg], otA0, 0, 0, 0);
      otA1 = __builtin_amdgcn_mfma_f32_32x32x16_bf16(vr[4 + cg], frA[cg], otA1, 0, 0, 0);
    }
#pragma unroll
    for (int cg = 0; cg < 4; ++cg) {
      otB0 = __builtin_amdgcn_mfma_f32_32x32x16_bf16(vr[cg],     frB[cg], otB0, 0, 0, 0);
      otB1 = __builtin_amdgcn_mfma_f32_32x32x16_bf16(vr[4 + cg], frB[cg], otB1, 0, 0, 0);
    }
    __builtin_amdgcn_s_setprio(0);
  };

#pragma unroll
  for (int p = 0; p < 4; ++p) {
    tile_body(p * 2,     kfA, kfB);
    tile_body(p * 2 + 1, kfB, kfA);
  }

  float liAa = liA + __shfl_xor(liA, 32);
  float liBa = liB + __shfl_xor(liB, 32);

  // ---- combine halves per group (two barrier passes) ----
  float* wreg = comb[wq4];
#pragma unroll
  for (int g = 0; g < 2; ++g) {
    f32x16 o0 = g ? otB0 : otA0;
    f32x16 o1 = g ? otB1 : otA1;
    float lig = g ? liBa : liAa;
    __syncthreads();
    if (half == 0) {
#pragma unroll
      for (int r = 0; r < 16; ++r) {
        wreg[r * 64 + lane]         = o0[r];
        wreg[(16 + r) * 64 + lane]  = o1[r];
      }
      wreg[2048 + lane] = lig;
    }
    __syncthreads();
    if (half == 1) {
      float inv = 1.f / (wreg[2048 + lane] + lig);
      u16* wb = wbuf[wq4];
#pragma unroll
      for (int dt = 0; dt < 2; ++dt) {
        f32x16 oo = dt ? o1 : o0;
#pragma unroll
        for (int gg = 0; gg < 4; ++gg) {
          float v0 = (wreg[(dt*16 + 4*gg+0)*64 + lane] + oo[4*gg+0]) * inv;
          float v1 = (wreg[(dt*16 + 4*gg+1)*64 + lane] + oo[4*gg+1]) * inv;
          float v2 = (wreg[(dt*16 + 4*gg+2)*64 + lane] + oo[4*gg+2]) * inv;
          float v3 = (wreg[(dt*16 + 4*gg+3)*64 + lane] + oo[4*gg+3]) * inv;
          unsigned p0, p1;
          asm("v_cvt_pk_bf16_f32 %0, %1, %2" : "=v"(p0) : "v"(v0), "v"(v1));
          asm("v_cvt_pk_bf16_f32 %0, %1, %2" : "=v"(p1) : "v"(v2), "v"(v3));
          int ch = dt * 8 + 2 * gg + hi;
          int pos = ch ^ ((lq & 7) << 1);
          uint2 wv; wv.x = p0; wv.y = p1;
          *(uint2*)((char*)wb + lq * 128 + pos * 8) = wv;
        }
      }
      int q2 = lane >> 1, j0 = lane & 1;
#pragma unroll
      for (int jj = 0; jj < 4; ++jj) {
        int j = j0 + jj * 2;
        uint4 val = *(const uint4*)((const char*)wb + q2 * 128 + ((j ^ (q2 & 7)) << 4));
        *(uint4*)(o + (size_t)(b * 1024 + qrow0 + g * 32 + q2) * 512 + h * 64 + j * 8) = val;
      }
    }
  }
}

extern "C" void kernel_launch(void* const* d_in, const int* in_sizes, int n_in,
                              void* d_out, int out_size, void* d_ws, size_t ws_size,
                              hipStream_t stream) {
  const float* x    = (const float*)d_in[0];
  const float* gn_w = (const float*)d_in[1];
  const float* gn_b = (const float*)d_in[2];
  const float* wq   = (const float*)d_in[3];
  const float* bq   = (const float*)d_in[4];
  const float* wk   = (const float*)d_in[5];
  const float* bk   = (const float*)d_in[6];
  const float* wv   = (const float*)d_in[7];
  const float* bv   = (const float*)d_in[8];
  const float* wp   = (const float*)d_in[9];
  const float* bp   = (const float*)d_in[10];

  char* ws = (char*)d_ws;
  float* part  = (float*)ws;                         // 4 KB
  float* bqkv  = (float*)(ws + 4096);                // 6 KB
  u16* wqkv = (u16*)(ws + 16384);                    // 1.5 MB [1536][512]
  u16* wpb  = (u16*)(ws + 1589248);                  // 512 KB
  u16* xn   = (u16*)(ws + 2113536);                  // 8 MB  [8192][512]
  u16* qb   = (u16*)(ws + 10502144);                 // 8 MB  Q row-major [8192][512]
  u16* kPb  = qb + 4194304;                          // 8 MB  K fragment-packed
  u16* vPb  = (u16*)(ws + 27279360);                 // 8 MB  V fragment-packed
  u16* attno = xn;                                   // alias: xn dead after QKV GEMM

  prep<<<1536, 256, 0, stream>>>(x, part,
      (const float4*)wq, (const float4*)wk, (const float4*)wv, (const float4*)wp,
      bq, bk, bv, wqkv, wpb, bqkv);
  gn_apply<<<dim3(32, 16, 8), dim3(32, 8), 0, stream>>>(x, part, gn_w, gn_b, xn);
  qkv_gemm<<<1536, 256, 0, stream>>>(xn, wqkv, bqkv, qb, kPb, vPb);
  attn_fwd<<<dim3(64, 4), 512, 0, stream>>>(qb, kPb, vPb, attno);
  proj_gemm<<<dim3(128, 4), 256, 0, stream>>>(wpb, attno, bp, x, (float*)d_out);
}

// Round 15
// 73.254 us; speedup vs baseline: 1.2520x; 1.2520x over previous
//
#include <hip/hip_runtime.h>
#include <stdint.h>

typedef unsigned short u16;
using bf16x8 = __attribute__((ext_vector_type(8))) short;
using f32x4  = __attribute__((ext_vector_type(4))) float;
using f32x16 = __attribute__((ext_vector_type(16))) float;
typedef unsigned int uv2 __attribute__((ext_vector_type(2)));

#define EPS_GN 1e-5f
#define SCL 0.18033688011112042f   // 0.125 * log2(e)

__device__ __forceinline__ u16 f2bf(float f) {
  union { float f; uint32_t u; } x; x.f = f;
  uint32_t r = x.u + 0x7FFFu + ((x.u >> 16) & 1u);
  return (u16)(r >> 16);
}

__device__ __forceinline__ void gload_lds16(const void* g, void* l) {
  __builtin_amdgcn_global_load_lds(
      (const __attribute__((address_space(1))) unsigned int*)g,
      (__attribute__((address_space(3))) unsigned int*)l, 16, 0, 0);
}

__device__ __forceinline__ void fence_tile() {
  asm volatile("s_waitcnt vmcnt(0)" ::: "memory");
  __builtin_amdgcn_s_barrier();
  __builtin_amdgcn_sched_barrier(0);
}

// ---------------- prep: GN partial sums (blocks 0..511) + weight cvt (blocks 512..1535) ----------------
__global__ __launch_bounds__(256) void prep(const float* __restrict__ x,
    float* __restrict__ part,
    const float4* __restrict__ wq, const float4* __restrict__ wk,
    const float4* __restrict__ wv, const float4* __restrict__ wp,
    const float* __restrict__ bq, const float* __restrict__ bk,
    const float* __restrict__ bv,
    u16* __restrict__ wqkv, u16* __restrict__ wpb, float* __restrict__ bqkv) {
  if (blockIdx.x < 512) {
    int bg = blockIdx.x >> 3, seg = blockIdx.x & 7;
    const float4* base = (const float4*)(x + (size_t)bg * 65536 + (size_t)seg * 8192);
    float s = 0.f, s2 = 0.f;
    for (int i = threadIdx.x; i < 2048; i += 256) {
      float4 v = base[i];
      s  += v.x + v.y + v.z + v.w;
      s2 += v.x*v.x + v.y*v.y + v.z*v.z + v.w*v.w;
    }
    for (int m = 1; m < 64; m <<= 1) { s += __shfl_xor(s, m); s2 += __shfl_xor(s2, m); }
    __shared__ float red[4][2];
    int wave = threadIdx.x >> 6;
    if ((threadIdx.x & 63) == 0) { red[wave][0] = s; red[wave][1] = s2; }
    __syncthreads();
    if (threadIdx.x == 0) {
      float a = 0.f, b = 0.f;
      for (int w = 0; w < 4; ++w) { a += red[w][0]; b += red[w][1]; }
      part[blockIdx.x * 2] = a; part[blockIdx.x * 2 + 1] = b;
    }
  } else {
    int i = (blockIdx.x - 512) * 256 + threadIdx.x;     // 0..262143
    int seg = i >> 16, j = i & 65535;
    const float4* w = (seg == 0) ? wq : (seg == 1) ? wk : (seg == 2) ? wv : wp;
    u16* o = (seg < 3) ? (wqkv + seg * 262144) : wpb;
    float sc = (seg == 0) ? SCL : 1.f;
    float4 v = w[j];
    o[j*4+0] = f2bf(v.x*sc); o[j*4+1] = f2bf(v.y*sc);
    o[j*4+2] = f2bf(v.z*sc); o[j*4+3] = f2bf(v.w*sc);
    if (i < 1536) bqkv[i] = (i < 512) ? bq[i]*SCL : (i < 1024) ? bk[i-512] : bv[i-1024];
  }
}

// ---------------- GN normalize + transpose [B,C,S] -> xn bf16 [B,S,C] (stats inline) ----------------
__global__ __launch_bounds__(256) void gn_apply(const float* __restrict__ x,
    const float* __restrict__ part, const float* __restrict__ w,
    const float* __restrict__ bb, u16* __restrict__ xn) {
  __shared__ float t[32][33];
  int s0 = blockIdx.x * 32, c0 = blockIdx.y * 32, b = blockIdx.z;
  int g = c0 >> 6;
  float s = 0.f, s2 = 0.f;
  for (int q = 0; q < 8; ++q) {
    s  += part[((b*8+g)*8 + q)*2];
    s2 += part[((b*8+g)*8 + q)*2 + 1];
  }
  float mean = s * (1.f/65536.f);
  float rstd = rsqrtf(s2 * (1.f/65536.f) - mean*mean + EPS_GN);
  for (int i = 0; i < 4; ++i) {
    int c = c0 + threadIdx.y + i * 8;
    float v = x[((size_t)b*512 + c)*1024 + s0 + threadIdx.x];
    t[threadIdx.y + i*8][threadIdx.x] = (v - mean) * rstd * w[c] + bb[c];
  }
  __syncthreads();
  for (int i = 0; i < 4; ++i) {
    int sdx = s0 + threadIdx.y + i * 8;
    xn[((size_t)b*1024 + sdx)*512 + c0 + threadIdx.x] = f2bf(t[threadIdx.x][threadIdx.y + i*8]);
  }
}

// ---------------- fused QKV GEMM: Out[m][n] = X[m][:]·W[n][:] + bias[n] ----------------
// 64(m) x 128(n) tiles, grid 1536: m = bx&127, n = bx>>7. LDS 48KB -> 3 blocks/CU.
// cols 0..1023 -> qkb row-major [8192][1024]
// cols 1024..1535 -> V fragment-packed: [(h*8+b)*16+tile][i=dt*4+cg][lane][8 bf16]
__global__ __launch_bounds__(256) void qkv_gemm(const u16* __restrict__ X,
    const u16* __restrict__ W, const float* __restrict__ bias,
    u16* __restrict__ qkb, u16* __restrict__ vP) {
  __shared__ __align__(16) u16 As[2*64*64];      // 16KB
  __shared__ __align__(16) u16 Bs[2*128*64];     // 32KB
  const int K = 512;
  int m0 = (blockIdx.x & 127) * 64, n0 = (blockIdx.x >> 7) * 128;
  int t = threadIdx.x, lane = t & 63, wave = t >> 6;
  int wm = wave >> 1, wn = wave & 1;
  int lr = lane & 15, lg = lane >> 4;
  f32x4 acc[2][4] = {};

  auto stage = [&](int k0, int bufi) {
    u16* Ab = As + bufi * 4096;
    u16* Bb = Bs + bufi * 8192;
#pragma unroll
    for (int c = 0; c < 2; ++c) {
      int chunk = wave * 2 + c;                  // 8 chunks x 1KB (A: 64 rows)
      int e = chunk * 512 + lane * 8;
      int r = e >> 6, col = e & 63;
      int scol = col ^ ((r & 7) << 3);
      gload_lds16(X + (size_t)(m0 + r) * K + k0 + scol, (char*)Ab + chunk * 1024);
    }
#pragma unroll
    for (int c = 0; c < 4; ++c) {
      int chunk = wave * 4 + c;                  // 16 chunks x 1KB (B: 128 rows)
      int e = chunk * 512 + lane * 8;
      int r = e >> 6, col = e & 63;
      int scol = col ^ ((r & 7) << 3);
      gload_lds16(W + (size_t)(n0 + r) * K + k0 + scol, (char*)Bb + chunk * 1024);
    }
  };

  stage(0, 0);
  fence_tile();
  int buf = 0;
  for (int k0 = 0; k0 < K; k0 += 64) {
    if (k0 + 64 < K) stage(k0 + 64, buf ^ 1);
    const char* Ab = (const char*)(As + buf * 4096);
    const char* Bb = (const char*)(Bs + buf * 8192);
    bf16x8 af[2][2], bfr[4][2];
#pragma unroll
    for (int kk = 0; kk < 2; ++kk) {
      int ca = kk * 64 + lg * 16;
#pragma unroll
      for (int i = 0; i < 2; ++i) {
        int ra = wm * 32 + i * 16 + lr;
        af[i][kk] = *(const bf16x8*)(Ab + ((ra * 128 + ca) ^ ((ra & 7) << 4)));
      }
#pragma unroll
      for (int j = 0; j < 4; ++j) {
        int rb = wn * 64 + j * 16 + lr;
        bfr[j][kk] = *(const bf16x8*)(Bb + ((rb * 128 + ca) ^ ((rb & 7) << 4)));
      }
    }
    __builtin_amdgcn_s_setprio(1);
#pragma unroll
    for (int kk = 0; kk < 2; ++kk)
#pragma unroll
      for (int i = 0; i < 2; ++i)
#pragma unroll
        for (int j = 0; j < 4; ++j)
          acc[i][j] = __builtin_amdgcn_mfma_f32_16x16x32_bf16(af[i][kk], bfr[j][kk], acc[i][j], 0, 0, 0);
    __builtin_amdgcn_s_setprio(0);
    fence_tile();
    buf ^= 1;
  }
  if (n0 < 1024) {
    for (int i = 0; i < 2; ++i)
      for (int j = 0; j < 4; ++j) {
        int col = n0 + wn * 64 + j * 16 + lr;
        float bv = bias[col];
        int rowb = m0 + wm * 32 + i * 16 + lg * 4;
        for (int r = 0; r < 4; ++r)
          qkb[(size_t)(rowb + r) * 1024 + col] = f2bf(acc[i][j][r] + bv);
      }
  } else {
    for (int i = 0; i < 2; ++i)
      for (int j = 0; j < 4; ++j) {
        int col = n0 + wn * 64 + j * 16 + lr;
        float bv = bias[col];
        int rowb = m0 + wm * 32 + i * 16 + lg * 4;   // %4==0
        int colV = col - 1024;
        int h  = colV >> 6, dl = colV & 63;
        int dt = dl >> 5,  lqv = dl & 31;
        int bb2 = rowb >> 10, s_in = rowb & 1023;
        int tile = s_in >> 6, kvl = s_in & 63;
        int cg = kvl >> 4, hiv = (kvl >> 3) & 1, j0 = kvl & 7;
        int ii = dt * 4 + cg, lv = hiv * 32 + lqv;
        size_t u16off = ((size_t)((h * 8 + bb2) * 16 + tile)) * 4096 + (ii * 64 + lv) * 8 + j0;
        unsigned p0, p1;
        float v0 = acc[i][j][0] + bv, v1 = acc[i][j][1] + bv;
        float v2 = acc[i][j][2] + bv, v3 = acc[i][j][3] + bv;
        asm("v_cvt_pk_bf16_f32 %0, %1, %2" : "=v"(p0) : "v"(v0), "v"(v1));
        asm("v_cvt_pk_bf16_f32 %0, %1, %2" : "=v"(p1) : "v"(v2), "v"(v3));
        uint2 pk; pk.x = p0; pk.y = p1;
        *(uint2*)(vP + u16off) = pk;
      }
  }
}

// ---------------- final projection (swapped): out[b][c][s] = Wp[c]·att[s][:] + bp[c] + x ----------------
__global__ __launch_bounds__(256) void proj_gemm(const u16* __restrict__ Wt,
    const u16* __restrict__ X, const float* __restrict__ bias,
    const float* __restrict__ resid, float* __restrict__ Out) {
  __shared__ __align__(16) u16 As[2*128*64];
  __shared__ __align__(16) u16 Bs[2*64*64];
  const int K = 512;
  int m0 = blockIdx.x * 64, n0 = blockIdx.y * 128;
  int t = threadIdx.x, lane = t & 63, wave = t >> 6;
  int wm = wave >> 1, wn = wave & 1;
  int lr = lane & 15, lg = lane >> 4;
  f32x4 acc[4][2] = {};

  auto stage = [&](int k0, int bufi) {
    u16* Ab = As + bufi * 8192;
    u16* Bb = Bs + bufi * 4096;
#pragma unroll
    for (int c = 0; c < 4; ++c) {
      int chunk = wave * 4 + c;
      int e = chunk * 512 + lane * 8;
      int r = e >> 6, col = e & 63;
      int scol = col ^ ((r & 7) << 3);
      gload_lds16(Wt + (size_t)(n0 + r) * K + k0 + scol, (char*)Ab + chunk * 1024);
    }
#pragma unroll
    for (int c = 0; c < 2; ++c) {
      int chunk = wave * 2 + c;
      int e = chunk * 512 + lane * 8;
      int r = e >> 6, col = e & 63;
      int scol = col ^ ((r & 7) << 3);
      gload_lds16(X + (size_t)(m0 + r) * K + k0 + scol, (char*)Bb + chunk * 1024);
    }
  };

  stage(0, 0);
  fence_tile();
  int buf = 0;
  for (int k0 = 0; k0 < K; k0 += 64) {
    if (k0 + 64 < K) stage(k0 + 64, buf ^ 1);
    const char* Ab = (const char*)(As + buf * 8192);
    const char* Bb = (const char*)(Bs + buf * 4096);
    bf16x8 af[4][2], bfr[2][2];
#pragma unroll
    for (int kk = 0; kk < 2; ++kk) {
      int ca = kk * 64 + lg * 16;
#pragma unroll
      for (int i = 0; i < 4; ++i) {
        int ra = wm * 64 + i * 16 + lr;
        af[i][kk] = *(const bf16x8*)(Ab + ((ra * 128 + ca) ^ ((ra & 7) << 4)));
      }
#pragma unroll
      for (int j = 0; j < 2; ++j) {
        int rb = wn * 32 + j * 16 + lr;
        bfr[j][kk] = *(const bf16x8*)(Bb + ((rb * 128 + ca) ^ ((rb & 7) << 4)));
      }
    }
    __builtin_amdgcn_s_setprio(1);
#pragma unroll
    for (int kk = 0; kk < 2; ++kk)
#pragma unroll
      for (int i = 0; i < 4; ++i)
#pragma unroll
        for (int j = 0; j < 2; ++j)
          acc[i][j] = __builtin_amdgcn_mfma_f32_16x16x32_bf16(af[i][kk], bfr[j][kk], acc[i][j], 0, 0, 0);
    __builtin_amdgcn_s_setprio(0);
    fence_tile();
    buf ^= 1;
  }
  for (int i = 0; i < 4; ++i)
    for (int j = 0; j < 2; ++j) {
      int mcol = m0 + wn * 32 + j * 16 + lr;
      for (int r = 0; r < 4; ++r) {
        int nrow = n0 + wm * 64 + i * 16 + lg * 4 + r;
        float v = acc[i][j][r] + bias[nrow];
        size_t b = (size_t)(mcol >> 10); int s = mcol & 1023;
        size_t addr = (b * 512 + nrow) * 1024 + s;
        Out[addr] = v + resid[addr];
      }
    }
}

// ---------------- flash attention: swapped 32x32, K in LDS (dbuf), V packed direct, KV-split x2 ----------------
// grid (64 bh, 8 qb). 8 waves: waves 0-3 KV[0,512), waves 4-7 KV[512,1024).
// Per tile: QK^T -> softmax (st->P) -> build fr[4] (P dies) -> load vr[8] (coalesced 1KB each) -> PV.
__global__ __launch_bounds__(512, 4) void attn_fwd(const u16* __restrict__ qk,
    const u16* __restrict__ vP, u16* __restrict__ o) {
  __shared__ __align__(16) u16 smem[26624];   // K stage 32KB | epilogue reuse 52KB
  int bh = blockIdx.x, qb = blockIdx.y;
  int b = bh >> 3, h = bh & 7;
  int t = threadIdx.x, lane = t & 63, wave = t >> 6;
  int half = wave >> 2, wq4 = wave & 3;
  int lq = lane & 31, hi = lane >> 5;
  int qrow0 = qb * 128 + wq4 * 32;
  const u16* qp = qk + (size_t)(b * 1024 + qrow0 + lq) * 1024 + h * 64 + hi * 8;
  bf16x8 qf[4];
#pragma unroll
  for (int s = 0; s < 4; ++s) qf[s] = *(const bf16x8*)(qp + s * 16);
  float li = 0.f;
  f32x16 ot[2] = {};
  int kvbase = half * 512;
  const u16* vb = vP + ((size_t)((h * 8 + b) * 16 + half * 8)) * 4096 + (size_t)lane * 8;

  auto stage = [&](int ti, int bufi) {
    u16* Kb = smem + (half * 2 + bufi) * 4096;
    int kv = kvbase + ti * 64;
#pragma unroll
    for (int c = 0; c < 2; ++c) {
      int chunk = wq4 * 2 + c;
      int e = chunk * 512 + lane * 8;
      int r = e >> 6, col = e & 63;
      int scol = col ^ ((r & 7) << 3);
      gload_lds16(qk + (size_t)(b * 1024 + kv + r) * 1024 + 512 + h * 64 + scol,
                  (char*)Kb + chunk * 1024);
    }
  };

  stage(0, 0);
  fence_tile();
  int buf = 0;
  for (int ti = 0; ti < 8; ++ti) {
    if (ti < 7) stage(ti + 1, buf ^ 1);
    const char* Kb = (const char*)(smem + (half * 2 + buf) * 4096);
    f32x16 st[2];
#pragma unroll
    for (int n2 = 0; n2 < 2; ++n2) {
      int rk = n2 * 32 + lq;
      f32x16 z = {};
      __builtin_amdgcn_s_setprio(1);
#pragma unroll
      for (int s = 0; s < 4; ++s) {
        bf16x8 kf = *(const bf16x8*)(Kb + ((rk * 128 + s * 32 + hi * 16) ^ ((rk & 7) << 4)));
        z = __builtin_amdgcn_mfma_f32_32x32x16_bf16(kf, qf[s], z, 0, 0, 0);
      }
      __builtin_amdgcn_s_setprio(0);
      st[n2] = z;
    }
    // max-free softmax: P = exp2(S) directly
    float sm[16];
#pragma unroll
    for (int r = 0; r < 16; ++r) {
      float e0 = __builtin_amdgcn_exp2f(st[0][r]);
      float e1 = __builtin_amdgcn_exp2f(st[1][r]);
      st[0][r] = e0; st[1][r] = e1;
      sm[r] = e0 + e1;
    }
#pragma unroll
    for (int s = 8; s > 0; s >>= 1)
#pragma unroll
      for (int r = 0; r < s; ++r) sm[r] += sm[r + s];
    li += sm[0] + __shfl_xor(sm[0], 32);
    // build all P fragments first (st dies, freeing regs before vr goes live)
    bf16x8 fr[4];
#pragma unroll
    for (int n2 = 0; n2 < 2; ++n2) {
#pragma unroll
      for (int c = 0; c < 2; ++c) {
        unsigned W0, W1, W2, W3;
        asm("v_cvt_pk_bf16_f32 %0, %1, %2" : "=v"(W0) : "v"(st[n2][8*c+0]), "v"(st[n2][8*c+1]));
        asm("v_cvt_pk_bf16_f32 %0, %1, %2" : "=v"(W1) : "v"(st[n2][8*c+2]), "v"(st[n2][8*c+3]));
        asm("v_cvt_pk_bf16_f32 %0, %1, %2" : "=v"(W2) : "v"(st[n2][8*c+4]), "v"(st[n2][8*c+5]));
        asm("v_cvt_pk_bf16_f32 %0, %1, %2" : "=v"(W3) : "v"(st[n2][8*c+6]), "v"(st[n2][8*c+7]));
        uv2 r02 = __builtin_amdgcn_permlane32_swap(W0, W2, false, false);
        uv2 r13 = __builtin_amdgcn_permlane32_swap(W1, W3, false, false);
        union { unsigned u[4]; bf16x8 v; } f;
        f.u[0] = r02[0]; f.u[1] = r13[0]; f.u[2] = r02[1]; f.u[3] = r13[1];
        fr[n2 * 2 + c] = f.v;
      }
    }
    // V fragments: 8 coalesced 1KB loads (L2-hot), consumed immediately by PV
    bf16x8 vr[8];
#pragma unroll
    for (int i = 0; i < 8; ++i) vr[i] = *(const bf16x8*)(vb + ti * 4096 + i * 512);
    __builtin_amdgcn_s_setprio(1);
#pragma unroll
    for (int cg = 0; cg < 4; ++cg)
#pragma unroll
      for (int dt = 0; dt < 2; ++dt)
        ot[dt] = __builtin_amdgcn_mfma_f32_32x32x16_bf16(vr[dt * 4 + cg], fr[cg], ot[dt], 0, 0, 0);
    __builtin_amdgcn_s_setprio(0);
    fence_tile();
    buf ^= 1;
  }
  // ---- combine the two KV halves: O = O0 + O1, li = li0 + li1 ----
  float* cbuf = (float*)smem;
  float* wreg = cbuf + wq4 * 2176;
  if (half == 0) {
#pragma unroll
    for (int dt = 0; dt < 2; ++dt)
#pragma unroll
      for (int r = 0; r < 16; ++r)
        wreg[(dt * 16 + r) * 64 + lane] = ot[dt][r];
    wreg[2048 + lane] = li;
  }
  __syncthreads();
  if (half == 1) {
    float inv = 1.f / (wreg[2048 + lane] + li);
    u16* wb = smem + 18432 + wq4 * 2048;   // [32 q][64 d] u16, 8B-chunk XOR swizzled
#pragma unroll
    for (int dt = 0; dt < 2; ++dt)
#pragma unroll
      for (int g = 0; g < 4; ++g) {
        float v0 = (wreg[(dt*16 + 4*g+0)*64 + lane] + ot[dt][4*g+0]) * inv;
        float v1 = (wreg[(dt*16 + 4*g+1)*64 + lane] + ot[dt][4*g+1]) * inv;
        float v2 = (wreg[(dt*16 + 4*g+2)*64 + lane] + ot[dt][4*g+2]) * inv;
        float v3 = (wreg[(dt*16 + 4*g+3)*64 + lane] + ot[dt][4*g+3]) * inv;
        unsigned p0, p1;
        asm("v_cvt_pk_bf16_f32 %0, %1, %2" : "=v"(p0) : "v"(v0), "v"(v1));
        asm("v_cvt_pk_bf16_f32 %0, %1, %2" : "=v"(p1) : "v"(v2), "v"(v3));
        int ch = dt * 8 + 2 * g + hi;          // d/4
        int pos = ch ^ ((lq & 7) << 1);
        uint2 wv; wv.x = p0; wv.y = p1;
        *(uint2*)((char*)wb + lq * 128 + pos * 8) = wv;
      }
    int q2 = lane >> 1, j0 = lane & 1;
#pragma unroll
    for (int jj = 0; jj < 4; ++jj) {
      int j = j0 + jj * 2;
      uint4 val = *(const uint4*)((const char*)wb + q2 * 128 + ((j ^ (q2 & 7)) << 4));
      *(uint4*)(o + (size_t)(b * 1024 + qrow0 + q2) * 512 + h * 64 + j * 8) = val;
    }
  }
}

extern "C" void kernel_launch(void* const* d_in, const int* in_sizes, int n_in,
                              void* d_out, int out_size, void* d_ws, size_t ws_size,
                              hipStream_t stream) {
  const float* x    = (const float*)d_in[0];
  const float* gn_w = (const float*)d_in[1];
  const float* gn_b = (const float*)d_in[2];
  const float* wq   = (const float*)d_in[3];
  const float* bq   = (const float*)d_in[4];
  const float* wk   = (const float*)d_in[5];
  const float* bk   = (const float*)d_in[6];
  const float* wv   = (const float*)d_in[7];
  const float* bv   = (const float*)d_in[8];
  const float* wp   = (const float*)d_in[9];
  const float* bp   = (const float*)d_in[10];

  char* ws = (char*)d_ws;
  float* part  = (float*)ws;                         // 4 KB
  float* bqkv  = (float*)(ws + 4096);                // 6 KB
  u16* wqkv = (u16*)(ws + 16384);                    // 1.5 MB [1536][512]
  u16* wpb  = (u16*)(ws + 1589248);                  // 512 KB
  u16* xn   = (u16*)(ws + 2113536);                  // 8 MB  [8192][512]
  u16* qkb  = (u16*)(ws + 10502144);                 // 16 MB [8192][1024]
  u16* vPb  = (u16*)(ws + 27279360);                 // 8 MB  V fragment-packed
  u16* attno = xn;                                   // alias: xn dead after QKV GEMM

  prep<<<1536, 256, 0, stream>>>(x, part,
      (const float4*)wq, (const float4*)wk, (const float4*)wv, (const float4*)wp,
      bq, bk, bv, wqkv, wpb, bqkv);
  gn_apply<<<dim3(32, 16, 8), dim3(32, 8), 0, stream>>>(x, part, gn_w, gn_b, xn);
  qkv_gemm<<<1536, 256, 0, stream>>>(xn, wqkv, bqkv, qkb, vPb);
  attn_fwd<<<dim3(64, 8), 512, 0, stream>>>(qkb, vPb, attno);
  proj_gemm<<<dim3(128, 4), 256, 0, stream>>>(wpb, attno, bp, x, (float*)d_out);
}